// Round 4
// baseline (416.359 us; speedup 1.0000x reference)
//
#include <hip/hip_runtime.h>
#include <hip/hip_bf16.h>

#define N_NODES 131072
#define DIM 128
#define NG 512

typedef __bf16 bf16;
typedef __attribute__((ext_vector_type(8))) __bf16 bf16x8;
typedef __attribute__((ext_vector_type(4))) float f32x4;

// 1/sqrt(128) * log2(e) — folded into Wk/bk so attention scores exp2 directly
#define KSC 0.12753785006196978f

// workspace layout (bytes)
#define WS_STARTS 0                         // 513 ints
#define WS_WF     8192                      // fragment-ordered W: 3*8*4*64*8 bf16 = 98304 B
#define WS_KB     131072                    // N*128 bf16
#define WS_QB     (131072 + 33554432)
#define WS_VTB    (131072 + 2*33554432)     // Vt[d][n]: 128 x N bf16

__global__ void seg_starts_kernel(const int* __restrict__ batch, int* __restrict__ starts) {
    int g = threadIdx.x;                    // 0..511
    int lo = 0, hi = N_NODES;
    while (lo < hi) { int mid = (lo + hi) >> 1; if (batch[mid] < g) lo = mid + 1; else hi = mid; }
    starts[g] = lo;
    if (g == 0) starts[NG] = N_NODES;
}

// Emit W in B-fragment order: Wf[((mat*8+n0)*4+ks)*64 + lane] is the bf16x8 that
// lane reads for MFMA (col = n0*16 + (lane&15), k = ks*32 + (lane>>4)*8 + j).
// Wk (mat 0) is pre-scaled by KSC so attention scores are exp2-ready.
__global__ void wconv_kernel(const float* __restrict__ Wk, const float* __restrict__ Wq,
                             const float* __restrict__ Wv, bf16* __restrict__ Wf) {
    int f = blockIdx.x * 256 + threadIdx.x;  // 0..6143
    int lane = f & 63, ks = (f >> 6) & 3, n0 = (f >> 8) & 7, mat = f >> 11;
    const float* src = (mat == 0) ? Wk : ((mat == 1) ? Wq : Wv);
    float sc = (mat == 0) ? KSC : 1.0f;
    int col = n0 * 16 + (lane & 15);
    int koff = ks * 32 + (lane >> 4) * 8;
    const float* p = src + col * DIM + koff;
    bf16* dst = Wf + (size_t)f * 8;
    #pragma unroll
    for (int j = 0; j < 8; j++) dst[j] = (bf16)(p[j] * sc);
}

// QKV projection (one matrix per blockIdx.y): out = x @ W^T + b, stored bf16.
// V stored transposed: Vt[d][n]. All global stores 16B coalesced via LDS tile.
__global__ __launch_bounds__(256) void qkv_kernel(
        const float* __restrict__ x, const bf16* __restrict__ Wf,
        const float* __restrict__ bk, const float* __restrict__ bq, const float* __restrict__ bv,
        bf16* __restrict__ Kb, bf16* __restrict__ Qb, bf16* __restrict__ Vtb) {
    __shared__ bf16 tile[128 * 136];         // 34816 B; x-tile first, then C-tile
    const int tid = threadIdx.x;
    const int w = tid >> 6, lane = tid & 63, q = lane >> 4, i = lane & 15;
    const int r0 = blockIdx.x * 128;
    const int mat = blockIdx.y;

    {   // stage x tile (coalesced fp32 loads -> bf16 LDS)
        #pragma unroll
        for (int it = 0; it < 16; it++) {
            int e = tid * 4 + it * 1024;     // element in 128x128 tile
            int row = e >> 7, col = e & 127;
            float4 u = *(const float4*)(x + (size_t)(r0 + row) * DIM + col);
            bf16 b[4] = {(bf16)u.x, (bf16)u.y, (bf16)u.z, (bf16)u.w};
            *(ushort4*)&tile[row * 136 + col] = *(ushort4*)b;
        }
    }
    __syncthreads();

    // A fragments from LDS: rows r0 + w*32 + rg*16 + i
    bf16x8 af[2][4];
    #pragma unroll
    for (int rg = 0; rg < 2; rg++)
        #pragma unroll
        for (int ks = 0; ks < 4; ks++)
            af[rg][ks] = *(const bf16x8*)&tile[(w * 32 + rg * 16 + i) * 136 + ks * 32 + q * 8];
    __syncthreads();                         // frag reads done before tile reuse

    const float* bias = (mat == 0) ? bk : ((mat == 1) ? bq : bv);
    const float bscale = (mat == 0) ? KSC : 1.0f;
    for (int n0 = 0; n0 < 8; n0++) {
        int col = n0 * 16 + i;
        float bias_v = bias[col] * bscale;
        f32x4 acc0 = {0,0,0,0}, acc1 = {0,0,0,0};
        #pragma unroll
        for (int ks = 0; ks < 4; ks++) {
            bf16x8 bw = *(const bf16x8*)(Wf + ((size_t)((mat * 8 + n0) * 4 + ks) * 64 + lane) * 8);
            acc0 = __builtin_amdgcn_mfma_f32_16x16x32_bf16(af[0][ks], bw, acc0, 0, 0, 0);
            acc1 = __builtin_amdgcn_mfma_f32_16x16x32_bf16(af[1][ks], bw, acc1, 0, 0, 0);
        }
        #pragma unroll
        for (int rg = 0; rg < 2; rg++) {
            f32x4 a = rg ? acc1 : acc0;
            #pragma unroll
            for (int r = 0; r < 4; r++) {
                int rowl = w * 32 + rg * 16 + q * 4 + r;
                bf16 hv = (bf16)(a[r] + bias_v);
                if (mat < 2) tile[rowl * 136 + col] = hv;   // row-major [row][d]
                else         tile[col * 136 + rowl] = hv;   // transposed [d][row]
            }
        }
    }
    __syncthreads();
    {   // coalesced 16B stores
        int row = tid >> 1, half = tid & 1;
        const uint4* src = (const uint4*)(tile + row * 136 + half * 64);
        uint4* dst;
        if (mat == 0)      dst = (uint4*)(Kb  + (size_t)(r0 + row) * DIM + half * 64);
        else if (mat == 1) dst = (uint4*)(Qb  + (size_t)(r0 + row) * DIM + half * 64);
        else               dst = (uint4*)(Vtb + (size_t)row * N_NODES + r0 + half * 64);
        #pragma unroll
        for (int j = 0; j < 8; j++) dst[j] = src[j];
    }
}

// Fused segment attention + residual + LayerNorm. 128 l-rows per block (8 waves).
// No max-subtraction (scores ~N(0,1.44), exp2-safe); li reduced once post-loop.
__global__ __launch_bounds__(512, 6) void attn_kernel(
        const float* __restrict__ x,
        const bf16* __restrict__ Kb, const bf16* __restrict__ Qb, const bf16* __restrict__ Vtb,
        const float* __restrict__ gamma, const float* __restrict__ beta,
        const int* __restrict__ starts, float* __restrict__ out) {
    __shared__ bf16 Qs[64 * 136];            // 17408 B
    __shared__ bf16 Vts[128 * 72];           // 18432 B
    __shared__ bf16 Ps[8 * 16 * 72];         // 18432 B   (total 54272 -> 3 blocks/CU)

    const int g = blockIdx.y;
    const int seg = starts[g];
    const int c = starts[g + 1] - seg;
    const int l0 = blockIdx.x * 128;
    if (l0 >= c) return;

    const int tid = threadIdx.x;
    const int w = tid >> 6, lane = tid & 63, q = lane >> 4, i = lane & 15;

    // K A-fragments direct from global (once per block; row clamped into segment)
    bf16x8 afK[4];
    {
        int lrow = l0 + w * 16 + i;
        if (lrow > c - 1) lrow = c - 1;
        const bf16* krow = Kb + (size_t)(seg + lrow) * DIM;
        #pragma unroll
        for (int ks = 0; ks < 4; ks++)
            afK[ks] = *(const bf16x8*)(krow + ks * 32 + q * 8);
    }

    float li[4] = {0.0f, 0.0f, 0.0f, 0.0f};
    f32x4 Oc[8];
    #pragma unroll
    for (int t = 0; t < 8; t++) Oc[t] = (f32x4){0,0,0,0};

    const int mstart = seg & ~7;             // 8-aligned -> 16B-aligned staging
    const int nch = (seg - mstart + c + 63) >> 6;
    for (int mc = 0; mc < nch; mc++) {
        const int mbase = mstart + (mc << 6);
        __syncthreads();                     // prev iter's Qs/Vts readers done
        {   // stage Q rows mbase..mbase+63 (row clamp vs N)
            int row = tid >> 3;
            int gr = mbase + row; if (gr > N_NODES - 1) gr = N_NODES - 1;
            const uint4* src = (const uint4*)(Qb + (size_t)gr * DIM);
            #pragma unroll
            for (int p = 0; p < 2; p++) {
                int slot = (tid & 7) + 8 * p;
                *(uint4*)&Qs[row * 136 + slot * 8] = src[slot];
            }
        }
        {   // stage Vts[d][m] = Vt[d][mbase+m]  (m-offset clamp vs N)
            int d = tid >> 2;
            #pragma unroll
            for (int p = 0; p < 2; p++) {
                int slot = (tid & 3) + 4 * p;
                int mo = mbase + slot * 8; if (mo > N_NODES - 8) mo = N_NODES - 8;
                uint4 v = *(const uint4*)(Vtb + (size_t)d * N_NODES + mo);
                *(uint4*)&Vts[d * 72 + slot * 8] = v;
            }
        }
        __syncthreads();

        // S = K * Q^T (per wave: 16 l-rows x 64 m-cols), pre-scaled for exp2
        f32x4 s[4];
        #pragma unroll
        for (int ti = 0; ti < 4; ti++) {
            f32x4 acc = {0,0,0,0};
            #pragma unroll
            for (int ks = 0; ks < 4; ks++) {
                bf16x8 bq = *(const bf16x8*)&Qs[(ti * 16 + i) * 136 + ks * 32 + q * 8];
                acc = __builtin_amdgcn_mfma_f32_16x16x32_bf16(afK[ks], bq, acc, 0, 0, 0);
            }
            s[ti] = acc;
        }
        if (mc == 0 || mc == nch - 1) {      // only edge chunks can have invalid m
            #pragma unroll
            for (int ti = 0; ti < 4; ti++) {
                int mg = mbase + ti * 16 + i;
                bool valid = (mg >= seg) && (mg < seg + c);
                #pragma unroll
                for (int r = 0; r < 4; r++)
                    s[ti][r] = valid ? s[ti][r] : -1.0e30f;
            }
        }

        // p = exp2(s); accumulate l per-lane; write P (C-layout -> A-layout, per-wave LDS)
        bf16* Pw = Ps + w * (16 * 72);
        #pragma unroll
        for (int ti = 0; ti < 4; ti++)
            #pragma unroll
            for (int r = 0; r < 4; r++) {
                float pv = exp2f(s[ti][r]);
                li[r] += pv;
                Pw[(q * 4 + r) * 72 + ti * 16 + i] = (bf16)pv;
            }

        bf16x8 afP[2];
        #pragma unroll
        for (int k2 = 0; k2 < 2; k2++)
            afP[k2] = *(const bf16x8*)&Pw[i * 72 + k2 * 32 + q * 8];
        #pragma unroll
        for (int dt = 0; dt < 8; dt++) {
            #pragma unroll
            for (int k2 = 0; k2 < 2; k2++) {
                bf16x8 bv = *(const bf16x8*)&Vts[(dt * 16 + i) * 72 + k2 * 32 + q * 8];
                Oc[dt] = __builtin_amdgcn_mfma_f32_16x16x32_bf16(afP[k2], bv, Oc[dt], 0, 0, 0);
            }
        }
    }

    // one-time l reduction across the 16 i-lanes
    #pragma unroll
    for (int st = 1; st < 16; st <<= 1)
        #pragma unroll
        for (int r = 0; r < 4; r++)
            li[r] += __shfl_xor(li[r], st);

    // epilogue: z = O/l, h = x + z, LayerNorm, store fp32
    float gv[8], bvv[8];
    #pragma unroll
    for (int ti = 0; ti < 8; ti++) { gv[ti] = gamma[ti * 16 + i]; bvv[ti] = beta[ti * 16 + i]; }
    for (int r = 0; r < 4; r++) {
        int lg = l0 + w * 16 + q * 4 + r;
        if (lg >= c) continue;               // uniform across the 16-lane shuffle group
        size_t node = (size_t)(seg + lg);
        float inv = 1.0f / li[r];
        const float* xr = x + node * DIM;
        float h[8], sum = 0.0f, ss = 0.0f;
        #pragma unroll
        for (int ti = 0; ti < 8; ti++) {
            float hv = xr[ti * 16 + i] + Oc[ti][r] * inv;
            h[ti] = hv;
            sum += hv; ss += hv * hv;
        }
        #pragma unroll
        for (int st = 1; st < 16; st <<= 1) {
            sum += __shfl_xor(sum, st);
            ss  += __shfl_xor(ss, st);
        }
        float mu = sum * (1.0f / 128.0f);
        float var = ss * (1.0f / 128.0f) - mu * mu;
        float rstd = rsqrtf(var + 1e-5f);
        float* op = out + node * DIM;
        #pragma unroll
        for (int ti = 0; ti < 8; ti++)
            op[ti * 16 + i] = (h[ti] - mu) * rstd * gv[ti] + bvv[ti];
    }
}

extern "C" void kernel_launch(void* const* d_in, const int* in_sizes, int n_in,
                              void* d_out, int out_size, void* d_ws, size_t ws_size,
                              hipStream_t stream) {
    (void)in_sizes; (void)n_in; (void)out_size; (void)ws_size;
    const float* x     = (const float*)d_in[0];
    const float* Wk    = (const float*)d_in[1];
    const float* bk    = (const float*)d_in[2];
    const float* Wq    = (const float*)d_in[3];
    const float* bq    = (const float*)d_in[4];
    const float* Wv    = (const float*)d_in[5];
    const float* bv    = (const float*)d_in[6];
    const float* gamma = (const float*)d_in[7];
    const float* beta  = (const float*)d_in[8];
    const int*   batch = (const int*)d_in[9];
    float* out = (float*)d_out;

    char* ws = (char*)d_ws;
    int*  starts = (int*)(ws + WS_STARTS);
    bf16* Wf  = (bf16*)(ws + WS_WF);
    bf16* Kb  = (bf16*)(ws + WS_KB);
    bf16* Qb  = (bf16*)(ws + WS_QB);
    bf16* Vtb = (bf16*)(ws + WS_VTB);

    seg_starts_kernel<<<1, 512, 0, stream>>>(batch, starts);
    wconv_kernel<<<24, 256, 0, stream>>>(Wk, Wq, Wv, Wf);
    qkv_kernel<<<dim3(1024, 3), 256, 0, stream>>>(x, Wf, bk, bq, bv, Kb, Qb, Vtb);
    attn_kernel<<<dim3(4, NG), 512, 0, stream>>>(x, Kb, Qb, Vtb, gamma, beta, starts, out);
}

// Round 5
// 277.453 us; speedup vs baseline: 1.5006x; 1.5006x over previous
//
#include <hip/hip_runtime.h>
#include <hip/hip_bf16.h>

#define N_NODES 131072
#define DIM 128
#define NG 512

typedef __bf16 bf16;
typedef __attribute__((ext_vector_type(8))) __bf16 bf16x8;
typedef __attribute__((ext_vector_type(4))) float f32x4;

// 1/sqrt(128) * log2(e) — folded into Wk/bk so attention scores exp2 directly
#define KSC 0.12753785006196978f

// workspace layout (bytes)
#define WS_STARTS 0                         // 513 ints
#define WS_WF     8192                      // fragment-ordered W: 3*8*4*64*8 bf16 = 98304 B
#define WS_KB     131072                    // N*128 bf16
#define WS_QB     (131072 + 33554432)
#define WS_VTB    (131072 + 2*33554432)     // Vt[d][n]: 128 x N bf16

__global__ void seg_starts_kernel(const int* __restrict__ batch, int* __restrict__ starts) {
    int g = threadIdx.x;                    // 0..511
    int lo = 0, hi = N_NODES;
    while (lo < hi) { int mid = (lo + hi) >> 1; if (batch[mid] < g) lo = mid + 1; else hi = mid; }
    starts[g] = lo;
    if (g == 0) starts[NG] = N_NODES;
}

// Emit W in B-fragment order: Wf[((mat*8+n0)*4+ks)*64 + lane] is the bf16x8 that
// lane reads for MFMA (col = n0*16 + (lane&15), k = ks*32 + (lane>>4)*8 + j).
// Wk (mat 0) is pre-scaled by KSC so attention scores are exp2-ready.
__global__ void wconv_kernel(const float* __restrict__ Wk, const float* __restrict__ Wq,
                             const float* __restrict__ Wv, bf16* __restrict__ Wf) {
    int f = blockIdx.x * 256 + threadIdx.x;  // 0..6143
    int lane = f & 63, ks = (f >> 6) & 3, n0 = (f >> 8) & 7, mat = f >> 11;
    const float* src = (mat == 0) ? Wk : ((mat == 1) ? Wq : Wv);
    float sc = (mat == 0) ? KSC : 1.0f;
    int col = n0 * 16 + (lane & 15);
    int koff = ks * 32 + (lane >> 4) * 8;
    const float* p = src + col * DIM + koff;
    bf16* dst = Wf + (size_t)f * 8;
    #pragma unroll
    for (int j = 0; j < 8; j++) dst[j] = (bf16)(p[j] * sc);
}

// QKV projection: out = x @ W^T + b, stored bf16 (x read ONCE per block, 3 mats).
// V stored transposed: Vt[d][n]. All global stores 16B coalesced via LDS tile.
__global__ __launch_bounds__(256) void qkv_kernel(
        const float* __restrict__ x, const bf16* __restrict__ Wf,
        const float* __restrict__ bk, const float* __restrict__ bq, const float* __restrict__ bv,
        bf16* __restrict__ Kb, bf16* __restrict__ Qb, bf16* __restrict__ Vtb) {
    __shared__ bf16 tile[128 * 136];         // 34816 B; x-tile first, then C-tile per mat
    const int tid = threadIdx.x;
    const int w = tid >> 6, lane = tid & 63, q = lane >> 4, i = lane & 15;
    const int r0 = blockIdx.x * 128;

    {   // stage x tile (coalesced fp32 loads -> bf16 LDS)
        #pragma unroll
        for (int it = 0; it < 16; it++) {
            int e = tid * 4 + it * 1024;     // element in 128x128 tile
            int row = e >> 7, col = e & 127;
            float4 u = *(const float4*)(x + (size_t)(r0 + row) * DIM + col);
            bf16 b[4] = {(bf16)u.x, (bf16)u.y, (bf16)u.z, (bf16)u.w};
            *(ushort4*)&tile[row * 136 + col] = *(ushort4*)b;
        }
    }
    __syncthreads();

    // A fragments from LDS: rows r0 + w*32 + rg*16 + i
    bf16x8 af[2][4];
    #pragma unroll
    for (int rg = 0; rg < 2; rg++)
        #pragma unroll
        for (int ks = 0; ks < 4; ks++)
            af[rg][ks] = *(const bf16x8*)&tile[(w * 32 + rg * 16 + i) * 136 + ks * 32 + q * 8];
    __syncthreads();                         // frag reads done before tile reuse

    for (int mat = 0; mat < 3; mat++) {
        const float* bias = (mat == 0) ? bk : ((mat == 1) ? bq : bv);
        const float bscale = (mat == 0) ? KSC : 1.0f;
        for (int n0 = 0; n0 < 8; n0++) {
            int col = n0 * 16 + i;
            float bias_v = bias[col] * bscale;
            f32x4 acc0 = {0,0,0,0}, acc1 = {0,0,0,0};
            #pragma unroll
            for (int ks = 0; ks < 4; ks++) {
                bf16x8 bw = *(const bf16x8*)(Wf + ((size_t)((mat * 8 + n0) * 4 + ks) * 64 + lane) * 8);
                acc0 = __builtin_amdgcn_mfma_f32_16x16x32_bf16(af[0][ks], bw, acc0, 0, 0, 0);
                acc1 = __builtin_amdgcn_mfma_f32_16x16x32_bf16(af[1][ks], bw, acc1, 0, 0, 0);
            }
            #pragma unroll
            for (int rg = 0; rg < 2; rg++) {
                f32x4 a = rg ? acc1 : acc0;
                #pragma unroll
                for (int r = 0; r < 4; r++) {
                    int rowl = w * 32 + rg * 16 + q * 4 + r;
                    bf16 hv = (bf16)(a[r] + bias_v);
                    if (mat < 2) tile[rowl * 136 + col] = hv;   // row-major [row][d]
                    else         tile[col * 136 + rowl] = hv;   // transposed [d][row]
                }
            }
        }
        __syncthreads();
        {   // coalesced 16B stores
            int row = tid >> 1, half = tid & 1;
            const uint4* src = (const uint4*)(tile + row * 136 + half * 64);
            uint4* dst;
            if (mat == 0)      dst = (uint4*)(Kb  + (size_t)(r0 + row) * DIM + half * 64);
            else if (mat == 1) dst = (uint4*)(Qb  + (size_t)(r0 + row) * DIM + half * 64);
            else               dst = (uint4*)(Vtb + (size_t)row * N_NODES + r0 + half * 64);
            #pragma unroll
            for (int j = 0; j < 8; j++) dst[j] = src[j];
        }
        __syncthreads();
    }
}

// Fused segment attention + residual + LayerNorm. 128 l-rows per block (8 waves).
// No max-subtraction (scores ~N(0,1.44), exp2-safe); li reduced once post-loop.
// launch_bounds(512,4): VGPR cap 128 — R4's (512,6) capped at 85 and spilled
// the accumulators to scratch (334 MB writes, 2x slowdown).
__global__ __launch_bounds__(512, 4) void attn_kernel(
        const float* __restrict__ x,
        const bf16* __restrict__ Kb, const bf16* __restrict__ Qb, const bf16* __restrict__ Vtb,
        const float* __restrict__ gamma, const float* __restrict__ beta,
        const int* __restrict__ starts, float* __restrict__ out) {
    __shared__ bf16 Qs[64 * 136];            // 17408 B
    __shared__ bf16 Vts[128 * 72];           // 18432 B
    __shared__ bf16 Ps[8 * 16 * 72];         // 18432 B   (total 54272 -> 2 blocks/CU w/ VGPR 128)

    const int g = blockIdx.y;
    const int seg = starts[g];
    const int c = starts[g + 1] - seg;
    const int l0 = blockIdx.x * 128;
    if (l0 >= c) return;

    const int tid = threadIdx.x;
    const int w = tid >> 6, lane = tid & 63, q = lane >> 4, i = lane & 15;

    // K A-fragments direct from global (once per block; row clamped into segment)
    bf16x8 afK[4];
    {
        int lrow = l0 + w * 16 + i;
        if (lrow > c - 1) lrow = c - 1;
        const bf16* krow = Kb + (size_t)(seg + lrow) * DIM;
        #pragma unroll
        for (int ks = 0; ks < 4; ks++)
            afK[ks] = *(const bf16x8*)(krow + ks * 32 + q * 8);
    }

    float li[4] = {0.0f, 0.0f, 0.0f, 0.0f};
    f32x4 Oc[8];
    #pragma unroll
    for (int t = 0; t < 8; t++) Oc[t] = (f32x4){0,0,0,0};

    const int mstart = seg & ~7;             // 8-aligned -> 16B-aligned staging
    const int nch = (seg - mstart + c + 63) >> 6;
    for (int mc = 0; mc < nch; mc++) {
        const int mbase = mstart + (mc << 6);
        __syncthreads();                     // prev iter's Qs/Vts readers done
        {   // stage Q rows mbase..mbase+63 (row clamp vs N)
            int row = tid >> 3;
            int gr = mbase + row; if (gr > N_NODES - 1) gr = N_NODES - 1;
            const uint4* src = (const uint4*)(Qb + (size_t)gr * DIM);
            #pragma unroll
            for (int p = 0; p < 2; p++) {
                int slot = (tid & 7) + 8 * p;
                *(uint4*)&Qs[row * 136 + slot * 8] = src[slot];
            }
        }
        {   // stage Vts[d][m] = Vt[d][mbase+m]  (m-offset clamp vs N)
            int d = tid >> 2;
            #pragma unroll
            for (int p = 0; p < 2; p++) {
                int slot = (tid & 3) + 4 * p;
                int mo = mbase + slot * 8; if (mo > N_NODES - 8) mo = N_NODES - 8;
                uint4 v = *(const uint4*)(Vtb + (size_t)d * N_NODES + mo);
                *(uint4*)&Vts[d * 72 + slot * 8] = v;
            }
        }
        __syncthreads();

        // S = K * Q^T (per wave: 16 l-rows x 64 m-cols), pre-scaled for exp2
        f32x4 s[4];
        #pragma unroll
        for (int ti = 0; ti < 4; ti++) {
            f32x4 acc = {0,0,0,0};
            #pragma unroll
            for (int ks = 0; ks < 4; ks++) {
                bf16x8 bq = *(const bf16x8*)&Qs[(ti * 16 + i) * 136 + ks * 32 + q * 8];
                acc = __builtin_amdgcn_mfma_f32_16x16x32_bf16(afK[ks], bq, acc, 0, 0, 0);
            }
            s[ti] = acc;
        }
        if (mc == 0 || mc == nch - 1) {      // only edge chunks can have invalid m
            #pragma unroll
            for (int ti = 0; ti < 4; ti++) {
                int mg = mbase + ti * 16 + i;
                bool valid = (mg >= seg) && (mg < seg + c);
                #pragma unroll
                for (int r = 0; r < 4; r++)
                    s[ti][r] = valid ? s[ti][r] : -1.0e30f;
            }
        }

        // p = exp2(s); accumulate l per-lane; write P (C-layout -> A-layout, per-wave LDS)
        bf16* Pw = Ps + w * (16 * 72);
        #pragma unroll
        for (int ti = 0; ti < 4; ti++)
            #pragma unroll
            for (int r = 0; r < 4; r++) {
                float pv = exp2f(s[ti][r]);
                li[r] += pv;
                Pw[(q * 4 + r) * 72 + ti * 16 + i] = (bf16)pv;
            }

        bf16x8 afP[2];
        #pragma unroll
        for (int k2 = 0; k2 < 2; k2++)
            afP[k2] = *(const bf16x8*)&Pw[i * 72 + k2 * 32 + q * 8];
        #pragma unroll
        for (int dt = 0; dt < 8; dt++) {
            #pragma unroll
            for (int k2 = 0; k2 < 2; k2++) {
                bf16x8 bv = *(const bf16x8*)&Vts[(dt * 16 + i) * 72 + k2 * 32 + q * 8];
                Oc[dt] = __builtin_amdgcn_mfma_f32_16x16x32_bf16(afP[k2], bv, Oc[dt], 0, 0, 0);
            }
        }
    }

    // one-time l reduction across the 16 i-lanes
    #pragma unroll
    for (int st = 1; st < 16; st <<= 1)
        #pragma unroll
        for (int r = 0; r < 4; r++)
            li[r] += __shfl_xor(li[r], st);

    // epilogue: z = O/l, h = x + z, LayerNorm, store fp32
    float gv[8], bvv[8];
    #pragma unroll
    for (int ti = 0; ti < 8; ti++) { gv[ti] = gamma[ti * 16 + i]; bvv[ti] = beta[ti * 16 + i]; }
    for (int r = 0; r < 4; r++) {
        int lg = l0 + w * 16 + q * 4 + r;
        if (lg >= c) continue;               // uniform across the 16-lane shuffle group
        size_t node = (size_t)(seg + lg);
        float inv = 1.0f / li[r];
        const float* xr = x + node * DIM;
        float h[8], sum = 0.0f, ss = 0.0f;
        #pragma unroll
        for (int ti = 0; ti < 8; ti++) {
            float hv = xr[ti * 16 + i] + Oc[ti][r] * inv;
            h[ti] = hv;
            sum += hv; ss += hv * hv;
        }
        #pragma unroll
        for (int st = 1; st < 16; st <<= 1) {
            sum += __shfl_xor(sum, st);
            ss  += __shfl_xor(ss, st);
        }
        float mu = sum * (1.0f / 128.0f);
        float var = ss * (1.0f / 128.0f) - mu * mu;
        float rstd = rsqrtf(var + 1e-5f);
        float* op = out + node * DIM;
        #pragma unroll
        for (int ti = 0; ti < 8; ti++)
            op[ti * 16 + i] = (h[ti] - mu) * rstd * gv[ti] + bvv[ti];
    }
}

extern "C" void kernel_launch(void* const* d_in, const int* in_sizes, int n_in,
                              void* d_out, int out_size, void* d_ws, size_t ws_size,
                              hipStream_t stream) {
    (void)in_sizes; (void)n_in; (void)out_size; (void)ws_size;
    const float* x     = (const float*)d_in[0];
    const float* Wk    = (const float*)d_in[1];
    const float* bk    = (const float*)d_in[2];
    const float* Wq    = (const float*)d_in[3];
    const float* bq    = (const float*)d_in[4];
    const float* Wv    = (const float*)d_in[5];
    const float* bv    = (const float*)d_in[6];
    const float* gamma = (const float*)d_in[7];
    const float* beta  = (const float*)d_in[8];
    const int*   batch = (const int*)d_in[9];
    float* out = (float*)d_out;

    char* ws = (char*)d_ws;
    int*  starts = (int*)(ws + WS_STARTS);
    bf16* Wf  = (bf16*)(ws + WS_WF);
    bf16* Kb  = (bf16*)(ws + WS_KB);
    bf16* Qb  = (bf16*)(ws + WS_QB);
    bf16* Vtb = (bf16*)(ws + WS_VTB);

    seg_starts_kernel<<<1, 512, 0, stream>>>(batch, starts);
    wconv_kernel<<<24, 256, 0, stream>>>(Wk, Wq, Wv, Wf);
    qkv_kernel<<<1024, 256, 0, stream>>>(x, Wf, bk, bq, bv, Kb, Qb, Vtb);
    attn_kernel<<<dim3(4, NG), 512, 0, stream>>>(x, Kb, Qb, Vtb, gamma, beta, starts, out);
}